// Round 12
// baseline (385.912 us; speedup 1.0000x reference)
//
#include <hip/hip_runtime.h>
#include <stdint.h>

typedef short short8 __attribute__((ext_vector_type(8)));
typedef short short4v __attribute__((ext_vector_type(4)));
typedef float floatx4 __attribute__((ext_vector_type(4)));
typedef unsigned uint4v __attribute__((ext_vector_type(4)));

#define H_  8
#define NB_ 4      // batch N
#define S_  1024
#define D_  512
#define KD_ 64

// fused "wait for prefetched global->LDS loads, then block barrier"
#define VM0_BARRIER() asm volatile("s_waitcnt vmcnt(0)\n\ts_barrier" ::: "memory")

__device__ __forceinline__ short f2bf(float f){
    unsigned u = __builtin_bit_cast(unsigned, f);
    u += 0x7fffu + ((u>>16)&1u);
    return (short)(u>>16);
}
__device__ __forceinline__ float wred_addf(float x){
    #pragma unroll
    for(int o=32;o>0;o>>=1) x += __shfl_xor(x,o,64);
    return x;
}
__device__ __forceinline__ float wred_maxf(float x){
    #pragma unroll
    for(int o=32;o>0;o>>=1) x = fmaxf(x,__shfl_xor(x,o,64));
    return x;
}
__device__ __forceinline__ unsigned umaxu(unsigned a, unsigned b){ return a>b?a:b; }
__device__ __forceinline__ unsigned uminu(unsigned a, unsigned b){ return a<b?a:b; }

// DPP-based wave64 reductions: pure VALU, result uniform via readlane.
template<int CTRL, int RMASK, int BC>
__device__ __forceinline__ unsigned dppu(unsigned x){
    return (unsigned)__builtin_amdgcn_update_dpp(0, (int)x, CTRL, RMASK, 0xf, BC);
}
template<int CTRL, int RMASK>
__device__ __forceinline__ unsigned dppu_m1(unsigned x){
    return (unsigned)__builtin_amdgcn_update_dpp((int)0xFFFFFFFF, (int)x, CTRL, RMASK, 0xf, 0);
}
__device__ __forceinline__ unsigned wsum_dpp_u(unsigned x){
    x += dppu<0x111,0xf,1>(x);
    x += dppu<0x112,0xf,1>(x);
    x += dppu<0x114,0xf,1>(x);
    x += dppu<0x118,0xf,1>(x);
    x += dppu<0x142,0xa,0>(x);
    x += dppu<0x143,0xc,0>(x);
    return (unsigned)__builtin_amdgcn_readlane((int)x, 63);
}
__device__ __forceinline__ unsigned wmax_dpp_u(unsigned x){
    x = umaxu(x, dppu<0x111,0xf,1>(x));
    x = umaxu(x, dppu<0x112,0xf,1>(x));
    x = umaxu(x, dppu<0x114,0xf,1>(x));
    x = umaxu(x, dppu<0x118,0xf,1>(x));
    x = umaxu(x, dppu<0x142,0xa,0>(x));
    x = umaxu(x, dppu<0x143,0xc,0>(x));
    return (unsigned)__builtin_amdgcn_readlane((int)x, 63);
}
__device__ __forceinline__ unsigned wmin_dpp_u(unsigned x){
    x = uminu(x, dppu_m1<0x111,0xf>(x));
    x = uminu(x, dppu_m1<0x112,0xf>(x));
    x = uminu(x, dppu_m1<0x114,0xf>(x));
    x = uminu(x, dppu_m1<0x118,0xf>(x));
    x = uminu(x, dppu_m1<0x142,0xa>(x));
    x = uminu(x, dppu_m1<0x143,0xc>(x));
    return (unsigned)__builtin_amdgcn_readlane((int)x, 63);
}
__device__ __forceinline__ float addu_f(float a, unsigned b){
    return a + __builtin_bit_cast(float, b);
}
__device__ __forceinline__ float wsum_dpp_f(float x){
    x = addu_f(x, dppu<0x111,0xf,1>(__builtin_bit_cast(unsigned,x)));
    x = addu_f(x, dppu<0x112,0xf,1>(__builtin_bit_cast(unsigned,x)));
    x = addu_f(x, dppu<0x114,0xf,1>(__builtin_bit_cast(unsigned,x)));
    x = addu_f(x, dppu<0x118,0xf,1>(__builtin_bit_cast(unsigned,x)));
    x = addu_f(x, dppu<0x142,0xa,0>(__builtin_bit_cast(unsigned,x)));
    x = addu_f(x, dppu<0x143,0xc,0>(__builtin_bit_cast(unsigned,x)));
    return __builtin_bit_cast(float, (unsigned)__builtin_amdgcn_readlane((int)__builtin_bit_cast(unsigned, x), 63));
}
__device__ __forceinline__ unsigned cvt_pk_bf16(float a, float b){
    unsigned r;
    asm("v_cvt_pk_bf16_f32 %0, %1, %2" : "=v"(r) : "v"(a), "v"(b));
    return r;
}
// hybrid top-k probe count: 8 elements on VALU (addc + DPP reduce),
// 8 elements on SALU (ballot + popcount).
__device__ __forceinline__ unsigned count128(const unsigned (&kv)[16], unsigned mid){
    unsigned cv = 0u;
    #pragma unroll
    for(int j=0;j<8;j++) cv += (unsigned)(kv[j] >= mid);
    unsigned cs = 0u;
    #pragma unroll
    for(int j=8;j<16;j++) cs += (unsigned)__popcll(__ballot(kv[j] >= mid));
    return wsum_dpp_u(cv) + cs;
}

// ---------------- merged prep: wtrans5 + wtrans4 + cvt2 + graph softmax ----------------
__global__ __launch_bounds__(256) void prep_kernel(
    const float* __restrict__ dWk, const float* __restrict__ dWv,
    const float* __restrict__ eWk, const float* __restrict__ eWv, const float* __restrict__ eWq,
    const float* __restrict__ dWo, const float* __restrict__ eWo,
    const float* __restrict__ W1, const float* __restrict__ W2,
    const float* __restrict__ y, const float* __restrict__ z,
    const float* __restrict__ g0, const float* __restrict__ g1,
    short* __restrict__ wKVd, short* __restrict__ wKVe, short* __restrict__ wQet,
    short* __restrict__ oWod, short* __restrict__ oWoe,
    short* __restrict__ oW1, short* __restrict__ oW2,
    short* __restrict__ y_bf, short* __restrict__ z_bf,
    short* __restrict__ og0, short* __restrict__ og1)
{
    __shared__ float t[32][33];
    int id = blockIdx.x;
    int tid = threadIdx.x;
    if(id < 1280){
        // wtrans5: per-head [512][64] -> [64][512] bf16
        int zz = id >> 5; int rem = id & 31; int by = rem >> 1, bx = rem & 1;
        int w = zz>>3, h = zz&7;
        const float* src; short* dst;
        if(w==0){ src = dWk + h*32768; dst = wKVd + h*65536; }
        else if(w==1){ src = dWv + h*32768; dst = wKVd + h*65536 + 32768; }
        else if(w==2){ src = eWk + h*32768; dst = wKVe + h*65536; }
        else if(w==3){ src = eWv + h*32768; dst = wKVe + h*65536 + 32768; }
        else { src = eWq + h*32768; dst = wQet + h*32768; }
        int c0 = bx*32, r0 = by*32;
        int r = tid>>3, cq = (tid&7)*4;
        #pragma unroll
        for(int i=0;i<4;i++) t[r][cq+i] = src[(r0+r)*64 + c0+cq+i];
        __syncthreads();
        int c = tid>>3, rq = (tid&7)*4;
        #pragma unroll
        for(int i=0;i<4;i++) dst[(c0+c)*512 + r0+rq+i] = f2bf(t[rq+i][c]);
    } else if(id < 3840){
        // wtrans4
        int id2 = id - 1280;
        const float* src; short* dst; int R, C, c0, r0;
        if(id2 < 512){
            src = (id2<256)? dWo : eWo; dst = (id2<256)? oWod : oWoe;
            int tt = id2 & 255; R = 512; C = 512;
            c0 = (tt&15)*32; r0 = (tt>>4)*32;
        } else if(id2 < 1536){
            src = W1; dst = oW1; int tt = id2 - 512; R = 512; C = 2048;
            c0 = (tt&63)*32; r0 = (tt>>6)*32;
        } else {
            src = W2; dst = oW2; int tt = id2 - 1536; R = 2048; C = 512;
            c0 = (tt&15)*32; r0 = (tt>>4)*32;
        }
        int r = tid>>3, cq = (tid&7)*4;
        #pragma unroll
        for(int i=0;i<4;i++) t[r][cq+i] = src[(long)(r0+r)*C + c0+cq+i];
        __syncthreads();
        int c = tid>>3, rq = (tid&7)*4;
        #pragma unroll
        for(int i=0;i<4;i++) dst[(long)(c0+c)*R + r0+rq+i] = f2bf(t[rq+i][c]);
    } else if(id < 7936){
        // cvt2: fp32 -> bf16 for y and z
        int tt = id - 3840;
        int bx = tt & 2047, by = tt >> 11;
        const float* in = by ? z : y;
        short* out = by ? z_bf : y_bf;
        int i = (bx*256 + tid)*4;
        floatx4 v = *(const floatx4*)(in + i);
        short4v r;
        #pragma unroll
        for(int j=0;j<4;j++) r[j] = f2bf(v[j]);
        *(short4v*)(out + i) = r;
    } else {
        // graph softmax -> 0.5*softmax bf16
        int tt = id - 7936;
        int row = tt & 1023, by = tt >> 10;
        const float* g = by ? g1 : g0;
        short* o = by ? og1 : og0;
        const float* gr = g + (long)row*S_;
        short* orow = o + (long)row*S_;
        int wave = tid>>6, lane = tid&63;
        float* red = &t[0][0];
        float v[4]; float mx = -3.0e38f;
        #pragma unroll
        for(int i=0;i<4;i++){ v[i] = gr[tid + 256*i]; mx = fmaxf(mx, v[i]); }
        mx = wred_maxf(mx);
        if(lane==0) red[wave] = mx;
        __syncthreads();
        mx = fmaxf(fmaxf(red[0],red[1]), fmaxf(red[2],red[3]));
        float s = 0.f;
        #pragma unroll
        for(int i=0;i<4;i++){ v[i] = __expf(v[i]-mx); s += v[i]; }
        s = wred_addf(s);
        if(lane==0) red[4+wave] = s;
        __syncthreads();
        s = red[4]+red[5]+red[6]+red[7];
        float inv = 0.5f/s;
        #pragma unroll
        for(int i=0;i<4;i++) orow[tid + 256*i] = f2bf(v[i]*inv);
    }
}

// ---------------- merged dec+enc KV projection (2-phase double-buffered) ----------------
__global__ __launch_bounds__(256) void gemm_projkv_kernel(
    const short* __restrict__ Ay, const short* __restrict__ Az,
    const short* __restrict__ Bd, const short* __restrict__ Be,
    const float* __restrict__ dbk, const float* __restrict__ dbv,
    const float* __restrict__ ebk, const float* __restrict__ ebv,
    short* __restrict__ Kd, short* __restrict__ Vd,
    short* __restrict__ Ke, short* __restrict__ Ve)
{
    __shared__ short As[2][64*32];
    __shared__ short Bs[2][128*32];
    int z = blockIdx.z; int enc = z>>3; int zl = z&7;
    const short* A  = enc ? Az : Ay;
    const short* Bb = (enc ? Be : Bd) + zl*65536;
    const float* b1 = enc ? ebk : dbk;
    const float* b2 = enc ? ebv : dbv;
    short* o1 = enc ? Ke : Kd;
    short* o2 = enc ? Ve : Vd;
    int m0 = blockIdx.x*64;
    int tid = threadIdx.x, wave = tid>>6, lane = tid&63, quad = lane>>4, nl = lane&15;
    int wm = (wave&1)*32, wn = (wave>>1)*64;
    floatx4 acc[2][4];
    #pragma unroll
    for(int i=0;i<2;i++)
        #pragma unroll
        for(int j=0;j<4;j++) acc[i][j] = (floatx4){0.f,0.f,0.f,0.f};
    int r = tid>>2, c = (tid&3)*8;
    auto stage = [&](int b, int k0){
        __builtin_amdgcn_global_load_lds(
            (const __attribute__((address_space(1))) unsigned*)(A + (long)(m0 + r)*512 + k0 + c),
            (__attribute__((address_space(3))) unsigned*)((char*)As[b] + wave*1024), 16, 0, 0);
        #pragma unroll
        for(int i=0;i<2;i++)
            __builtin_amdgcn_global_load_lds(
                (const __attribute__((address_space(1))) unsigned*)(Bb + (long)(r + i*64)*512 + k0 + c),
                (__attribute__((address_space(3))) unsigned*)((char*)Bs[b] + i*4096 + wave*1024), 16, 0, 0);
    };
    stage(0, 0);
    VM0_BARRIER();
    int cur = 0;
    for(int k0=0;k0<512;k0+=32){
        if(k0 + 32 < 512) stage(cur^1, k0+32);
        short8 af[2], bfr[4];
        #pragma unroll
        for(int i=0;i<2;i++) af[i] = *(const short8*)(As[cur] + (wm + i*16 + nl)*32 + quad*8);
        #pragma unroll
        for(int j=0;j<4;j++) bfr[j] = *(const short8*)(Bs[cur] + (wn + j*16 + nl)*32 + quad*8);
        #pragma unroll
        for(int i=0;i<2;i++)
            #pragma unroll
            for(int j=0;j<4;j++)
                acc[i][j] = __builtin_amdgcn_mfma_f32_16x16x32_bf16(af[i],bfr[j],acc[i][j],0,0,0);
        VM0_BARRIER();
        cur ^= 1;
    }
    #pragma unroll
    for(int j=0;j<4;j++){
        int n = wn + j*16 + nl;
        float bv = (n >= 64) ? b2[zl*64 + n - 64] : b1[zl*64 + n];
        #pragma unroll
        for(int i=0;i<2;i++){
            #pragma unroll
            for(int rr=0;rr<4;rr++){
                int m = m0 + wm + i*16 + quad*4 + rr;
                float v = acc[i][j][rr] + bv;
                long zb = (long)(zl*NB_ + (m>>10));
                if(n >= 64) o2[ (zb*KD_ + (n-64))*S_ + (m&1023) ] = f2bf(v);
                else        o1[ (zb*S_ + (m&1023))*KD_ + n ] = f2bf(v);
            }
        }
    }
}

// ---------------- projection GEMM for Q (2-phase double-buffered) ----------------
__global__ __launch_bounds__(256) void gemm_projq_kernel(
    const short* __restrict__ A, const short* __restrict__ Bt,
    const float* __restrict__ b1, short* __restrict__ o1)
{
    __shared__ short As[2][64*32];
    __shared__ short Bs[2][64*32];
    int z = blockIdx.z;
    int m0 = blockIdx.x*64;
    const short* Bb = Bt + (long)z*(64*512);
    int tid = threadIdx.x, wave = tid>>6, lane = tid&63, quad = lane>>4, nl = lane&15;
    int wm = (wave&1)*32, wn = (wave>>1)*32;
    floatx4 acc[2][2];
    #pragma unroll
    for(int i=0;i<2;i++)
        #pragma unroll
        for(int j=0;j<2;j++) acc[i][j] = (floatx4){0.f,0.f,0.f,0.f};
    int r = tid>>2, c = (tid&3)*8;
    auto stage = [&](int b, int k0){
        __builtin_amdgcn_global_load_lds(
            (const __attribute__((address_space(1))) unsigned*)(A + (long)(m0 + r)*512 + k0 + c),
            (__attribute__((address_space(3))) unsigned*)((char*)As[b] + wave*1024), 16, 0, 0);
        __builtin_amdgcn_global_load_lds(
            (const __attribute__((address_space(1))) unsigned*)(Bb + (long)r*512 + k0 + c),
            (__attribute__((address_space(3))) unsigned*)((char*)Bs[b] + wave*1024), 16, 0, 0);
    };
    stage(0, 0);
    VM0_BARRIER();
    int cur = 0;
    for(int k0=0;k0<512;k0+=32){
        if(k0 + 32 < 512) stage(cur^1, k0+32);
        short8 af[2], bfr[2];
        #pragma unroll
        for(int i=0;i<2;i++) af[i] = *(const short8*)(As[cur] + (wm + i*16 + nl)*32 + quad*8);
        #pragma unroll
        for(int j=0;j<2;j++) bfr[j] = *(const short8*)(Bs[cur] + (wn + j*16 + nl)*32 + quad*8);
        #pragma unroll
        for(int i=0;i<2;i++)
            #pragma unroll
            for(int j=0;j<2;j++)
                acc[i][j] = __builtin_amdgcn_mfma_f32_16x16x32_bf16(af[i],bfr[j],acc[i][j],0,0,0);
        VM0_BARRIER();
        cur ^= 1;
    }
    #pragma unroll
    for(int j=0;j<2;j++){
        int n = wn + j*16 + nl;
        float bv = b1[z*64 + n];
        #pragma unroll
        for(int i=0;i<2;i++){
            #pragma unroll
            for(int rr=0;rr<4;rr++){
                int m = m0 + wm + i*16 + quad*4 + rr;
                float v = acc[i][j][rr] + bv;
                long zb = (long)(z*NB_ + (m>>10));
                o1[ (zb*S_ + (m&1023))*KD_ + n ] = f2bf(v);
            }
        }
    }
}

// ---------------- big MFMA GEMM, m97 pattern, 2-phase double-buffered ----------------
template<int TM, int TN, int OUTBF, int RELU>
__global__ __launch_bounds__(256) void gemm_big_kernel(
    const short* __restrict__ A, const short* __restrict__ Bt, const float* __restrict__ bias,
    void* __restrict__ out, int M, int N, int K)
{
    __shared__ short As[2][TM*32];
    __shared__ short Bs[2][TN*32];
    int m0 = blockIdx.x*TM, n0 = blockIdx.y*TN;
    int tid = threadIdx.x, wave = tid>>6, lane = tid&63, quad = lane>>4, nl = lane&15;
    constexpr int MI = TM/32, NI = TN/32;
    int wm = (wave&1)*(TM/2), wn = (wave>>1)*(TN/2);
    floatx4 acc[MI][NI];
    #pragma unroll
    for(int i=0;i<MI;i++)
        #pragma unroll
        for(int j=0;j<NI;j++) acc[i][j] = (floatx4){0.f,0.f,0.f,0.f};

    int r = tid>>2, c = (tid&3)*8;
    auto stage = [&](int b, int k0){
        #pragma unroll
        for(int i=0;i<TM/64;i++)
            __builtin_amdgcn_global_load_lds(
                (const __attribute__((address_space(1))) unsigned*)(A + (long)(m0 + r + i*64)*K + k0 + c),
                (__attribute__((address_space(3))) unsigned*)((char*)As[b] + i*4096 + wave*1024),
                16, 0, 0);
        #pragma unroll
        for(int i=0;i<TN/64;i++)
            __builtin_amdgcn_global_load_lds(
                (const __attribute__((address_space(1))) unsigned*)(Bt + (long)(n0 + r + i*64)*K + k0 + c),
                (__attribute__((address_space(3))) unsigned*)((char*)Bs[b] + i*4096 + wave*1024),
                16, 0, 0);
    };
    stage(0, 0);
    VM0_BARRIER();
    int cur = 0;
    for(int k0=0;k0<K;k0+=32){
        if(k0 + 32 < K) stage(cur^1, k0+32);
        short8 af[MI], bfr[NI];
        #pragma unroll
        for(int i=0;i<MI;i++) af[i] = *(const short8*)(As[cur] + (wm + i*16 + nl)*32 + quad*8);
        #pragma unroll
        for(int j=0;j<NI;j++) bfr[j] = *(const short8*)(Bs[cur] + (wn + j*16 + nl)*32 + quad*8);
        #pragma unroll
        for(int i=0;i<MI;i++)
            #pragma unroll
            for(int j=0;j<NI;j++)
                acc[i][j] = __builtin_amdgcn_mfma_f32_16x16x32_bf16(af[i],bfr[j],acc[i][j],0,0,0);
        VM0_BARRIER();
        cur ^= 1;
    }
    #pragma unroll
    for(int j=0;j<NI;j++){
        int n = n0 + wn + j*16 + nl;
        float bv = bias[n];
        #pragma unroll
        for(int i=0;i<MI;i++){
            #pragma unroll
            for(int rr=0;rr<4;rr++){
                int m = m0 + wm + i*16 + quad*4 + rr;
                float v = acc[i][j][rr] + bv;
                if(RELU) v = fmaxf(v, 0.f);
                if(OUTBF) ((short*)out)[(long)m*N + n] = f2bf(v);
                else      ((float*)out)[(long)m*N + n] = v;
            }
        }
    }
}

// ---------------- fused attention v13: r6 search, phase-2 rows software-pipelined ----------------
// Row B's LDS/graph loads and key-build/max-tree hoisted before row A's search so
// their latency and VALU work fill the search's DPP-chain bubbles. Searches run
// sequentially (r3's lockstep interleave regressed). Epilogues reconstruct bf16
// from the monotone key (inverse verified in r3) so the pr[] arrays are dropped.
__global__ __launch_bounds__(512,6) void attn_kernel(
    const short* __restrict__ Qb, const short* __restrict__ Kb, const short* __restrict__ Vt,
    const short* __restrict__ graph, short* __restrict__ ctx, int causal)
{
    __shared__ short attb[16*1024];   // 32 KiB
    __shared__ float pbuf[16*68];     // 4.25 KiB
    int hn = blockIdx.x, qt = blockIdx.y;
    int h = hn>>2, n = hn&3;
    int q0 = qt*16;
    int tid=threadIdx.x, wave=tid>>6, lane=tid&63, quad=lane>>4, nl=lane&15;

    if(causal){
        uint4v fv = (uint4v){0xff80ff80u,0xff80ff80u,0xff80ff80u,0xff80ff80u};
        #pragma unroll
        for(int i=0;i<4;i++) *(uint4v*)((char*)attb + tid*16 + i*8192) = fv;
        __syncthreads();
    }

    // ---- phase 1: scores -> bf16 LDS (rot 8q), diagonal tile masked to -inf ----
    const short* Qp = Qb + ((long)hn*S_ + q0 + nl)*KD_ + quad*8;
    short8 aq0 = *(const short8*)(Qp);
    short8 aq1 = *(const short8*)(Qp + 32);
    const short* Kp = Kb + (long)hn*S_*KD_;
    int stmax = causal ? qt : 63;
    for(int st=wave; st<=stmax; st+=8){
        const short* kp = Kp + (st*16 + nl)*KD_ + quad*8;
        short8 b0 = *(const short8*)(kp);
        short8 b1 = *(const short8*)(kp + 32);
        floatx4 cc = (floatx4){0.f,0.f,0.f,0.f};
        cc = __builtin_amdgcn_mfma_f32_16x16x32_bf16(aq0,b0,cc,0,0,0);
        cc = __builtin_amdgcn_mfma_f32_16x16x32_bf16(aq1,b1,cc,0,0,0);
        int s = st*16 + nl;
        #pragma unroll
        for(int rr=0;rr<4;rr++){
            int q = quad*4 + rr;
            short val = f2bf(cc[rr]*0.125f);
            if(causal && s > q0 + q) val = (short)0xff80;   // -inf
            attb[q*1024 + ((s + 8*q)&1023)] = val;
        }
    }
    __syncthreads();

    // ---- phase 2: two rows per wave, loads+builds hoisted, searches sequential ----
    {
        int qA = wave*2, qB = qA + 1;
        short* rowA = attb + qA*1024;
        short* rowB = attb + qB*1024;
        int sb = lane*16;
        int pA = (sb + 8*qA) & 1023;
        int pB = (sb + 8*qB) & 1023;
        const short* gAp = graph + (long)(q0+qA)*1024 + sb;
        const short* gBp = graph + (long)(q0+qB)*1024 + sb;
        uint4v gA0 = *(const uint4v*)(gAp);
        uint4v gA1 = *(const uint4v*)(gAp + 8);
        uint4v gB0 = *(const uint4v*)(gBp);
        uint4v gB1 = *(const uint4v*)(gBp + 8);
        uint4v uA0 = *(const uint4v*)(rowA + pA);
        uint4v uA1 = *(const uint4v*)(rowA + ((pA+8)&1023));
        uint4v uB0 = *(const uint4v*)(rowB + pB);
        uint4v uB1 = *(const uint4v*)(rowB + ((pB+8)&1023));

        // monotone 16-bit keys for both rows
        unsigned kvA[16], kvB[16];
        #pragma unroll
        for(int i=0;i<4;i++){
            unsigned u, kp;
            u = uA0[i]; kp = u ^ (0x80008000u + ((u>>15)&0x00010001u)*0x7fffu);
            kvA[2*i] = kp & 0xffffu; kvA[2*i+1] = kp >> 16;
            u = uA1[i]; kp = u ^ (0x80008000u + ((u>>15)&0x00010001u)*0x7fffu);
            kvA[8+2*i] = kp & 0xffffu; kvA[8+2*i+1] = kp >> 16;
            u = uB0[i]; kp = u ^ (0x80008000u + ((u>>15)&0x00010001u)*0x7fffu);
            kvB[2*i] = kp & 0xffffu; kvB[2*i+1] = kp >> 16;
            u = uB1[i]; kp = u ^ (0x80008000u + ((u>>15)&0x00010001u)*0x7fffu);
            kvB[8+2*i] = kp & 0xffffu; kvB[8+2*i+1] = kp >> 16;
        }
        // per-lane max trees (independent -> ILP)
        unsigned mkA, mkB;
        {
            unsigned a0 = umaxu(kvA[0],kvA[1]),  a1 = umaxu(kvA[2],kvA[3]);
            unsigned a2 = umaxu(kvA[4],kvA[5]),  a3 = umaxu(kvA[6],kvA[7]);
            unsigned a4 = umaxu(kvA[8],kvA[9]),  a5 = umaxu(kvA[10],kvA[11]);
            unsigned a6 = umaxu(kvA[12],kvA[13]),a7 = umaxu(kvA[14],kvA[15]);
            mkA = umaxu(umaxu(umaxu(a0,a1),umaxu(a2,a3)), umaxu(umaxu(a4,a5),umaxu(a6,a7)));
            unsigned b0 = umaxu(kvB[0],kvB[1]),  b1 = umaxu(kvB[2],kvB[3]);
            unsigned b2 = umaxu(kvB[4],kvB[5]),  b3 = umaxu(kvB[6],kvB[7]);
            unsigned b4 = umaxu(kvB[8],kvB[9]),  b5 = umaxu(kvB[10],kvB[11]);
            unsigned b6 = umaxu(kvB[12],kvB[13]),b7 = umaxu(kvB[14],kvB[15]);
            mkB = umaxu(umaxu(umaxu(b0,b1),umaxu(b2,b3)), umaxu(umaxu(b4,b5),umaxu(b6,b7)));
        }
        unsigned mksA = wmax_dpp_u(mkA);
        unsigned mksB = wmax_dpp_u(mkB);
        unsigned lminA = wmin_dpp_u(mkA);
        unsigned lminB = wmin_dpp_u(mkB);

        // ---- search A ----
        unsigned loA, hiA;
        {
            unsigned cnt = count128(kvA, lminA);
            if(cnt >= 128u){ loA = lminA; hiA = (cnt == 128u) ? (lminA + 1u) : (mksA + 1u); }
            else           { loA = 0u;   hiA = lminA; }
        }
        while(hiA - loA > 1u){
            unsigned mid = (loA + hiA) >> 1;
            unsigned cnt = count128(kvA, mid);
            if(cnt >= 128u){ loA = mid; if(cnt == 128u) break; }
            else hiA = mid;
        }
        // ---- epilogue A (reconstruct bf16 from keys) ----
        {
            unsigned uo = (mksA & 0x8000u) ? ((mksA & 0x7fffu)<<16) : ((~mksA)<<16);
            float mxf = __builtin_bit_cast(float, uo);
            float ev[16]; float sm = 0.f;
            #pragma unroll
            for(int j=0;j<16;j++){
                unsigned k = kvA[j];
                unsigned ub = (k & 0x8000u) ? (k ^ 0x8000u) : ((~k) & 0xffffu);
                float f = __builtin_bit_cast(float, ub << 16);
                float e = __expf(f - mxf);
                e = (k >= loA) ? e : 0.f;
                ev[j] = e; sm += e;
            }
            sm = wsum_dpp_f(sm);
            float inv = 0.5f / sm;   // (1-gw)=0.5; graph holds 0.5*softmax
            uint4v w0, w1;
            #pragma unroll
            for(int i=0;i<4;i++){
                float gl0 = __builtin_bit_cast(float, gA0[i] << 16);
                float gh0 = __builtin_bit_cast(float, gA0[i] & 0xffff0000u);
                w0[i] = cvt_pk_bf16(fmaf(ev[2*i], inv, gl0), fmaf(ev[2*i+1], inv, gh0));
                float gl1 = __builtin_bit_cast(float, gA1[i] << 16);
                float gh1 = __builtin_bit_cast(float, gA1[i] & 0xffff0000u);
                w1[i] = cvt_pk_bf16(fmaf(ev[8+2*i], inv, gl1), fmaf(ev[8+2*i+1], inv, gh1));
            }
            *(uint4v*)(rowA + pA) = w0;
            *(uint4v*)(rowA + ((pA+8)&1023)) = w1;
        }
        // ---- search B ----
        unsigned loB, hiB;
        {
            unsigned cnt = count128(kvB, lminB);
            if(cnt >= 128u){ loB = lminB; hiB = (cnt == 128u) ? (lminB + 1u) : (mksB + 1u); }
            else           { loB = 0u;   hiB = lminB; }
        }
        while(hiB - loB > 1u){
            unsigned mid = (loB + hiB) >> 1;
            unsigned cnt = count128(kvB, mid);
            if(cnt >= 128u){ loB = mid; if(cnt == 128u) break; }
            else hiB = mid;
        }
        // ---- epilogue B ----
        {
            unsigned uo = (mksB & 0x8000u) ? ((mksB & 0x7fffu)<<16) : ((~mksB)<<16);
            float mxf = __builtin_bit_cast(float, uo);
            float ev[16]; float sm = 0.f;
            #pragma unroll
            for(int j=0;j<16;j++){
                unsigned k = kvB[j];
                unsigned ub = (k & 0x8000u) ? (k ^ 0x8000u) : ((~k) & 0xffffu);
                float f = __builtin_bit_cast(float, ub << 16);
                float e = __expf(f - mxf);
                e = (k >= loB) ? e : 0.f;
                ev[j] = e; sm += e;
            }
            sm = wsum_dpp_f(sm);
            float inv = 0.5f / sm;
            uint4v w0, w1;
            #pragma unroll
            for(int i=0;i<4;i++){
                float gl0 = __builtin_bit_cast(float, gB0[i] << 16);
                float gh0 = __builtin_bit_cast(float, gB0[i] & 0xffff0000u);
                w0[i] = cvt_pk_bf16(fmaf(ev[2*i], inv, gl0), fmaf(ev[2*i+1], inv, gh0));
                float gl1 = __builtin_bit_cast(float, gB1[i] << 16);
                float gh1 = __builtin_bit_cast(float, gB1[i] & 0xffff0000u);
                w1[i] = cvt_pk_bf16(fmaf(ev[8+2*i], inv, gl1), fmaf(ev[8+2*i+1], inv, gh1));
            }
            *(uint4v*)(rowB + pB) = w0;
            *(uint4v*)(rowB + ((pB+8)&1023)) = w1;
        }
    }
    __syncthreads();

    // ---- phase 3: ctx = att @ V, split over s-halves (sh), v-quarters (vh) ----
    int vh = wave & 3, sh = wave >> 2;
    int v0 = vh*16;
    const short* Vp = Vt + ((long)hn*KD_ + v0 + nl)*S_;
    floatx4 o4 = (floatx4){0.f,0.f,0.f,0.f};
    int arow = nl;
    int sbase = sh*512;
    for(int s0=sbase; s0<sbase+512; s0+=32){
        int cs = (s0 + quad*8 + 8*arow) & 1023;
        short8 ap = *(const short8*)(attb + arow*1024 + cs);
        short8 bv = *(const short8*)(Vp + s0 + quad*8);
        o4 = __builtin_amdgcn_mfma_f32_16x16x32_bf16(ap,bv,o4,0,0,0);
    }
    if(sh==1){
        #pragma unroll
        for(int rr=0;rr<4;rr++) pbuf[(quad*4+rr)*68 + v0 + nl] = o4[rr];
    }
    __syncthreads();
    if(sh==0){
        #pragma unroll
        for(int rr=0;rr<4;rr++){
            int q = quad*4 + rr;
            float v = o4[rr] + pbuf[q*68 + v0 + nl];
            ctx[ ((long)(n*S_ + q0 + q))*512 + h*KD_ + v0 + nl ] = f2bf(v);
        }
    }
}

// ---------------- LayerNorm(x + res) ----------------
__global__ __launch_bounds__(256) void ln_kernel(const float* __restrict__ x, const float* __restrict__ res,
                                                 float* __restrict__ outf, short* __restrict__ outb){
    long row = blockIdx.x;
    const float* xr = x + row*D_;
    const float* rr = res + row*D_;
    int tid = threadIdx.x, wave = tid>>6, lane = tid&63;
    float t0 = xr[tid] + rr[tid];
    float t1 = xr[tid+256] + rr[tid+256];
    float s = t0 + t1, s2 = t0*t0 + t1*t1;
    __shared__ float red[8];
    s = wred_addf(s); s2 = wred_addf(s2);
    if(lane==0){ red[wave] = s; red[4+wave] = s2; }
    __syncthreads();
    s  = red[0]+red[1]+red[2]+red[3];
    s2 = red[4]+red[5]+red[6]+red[7];
    float mean = s*(1.f/512.f);
    float var = s2*(1.f/512.f) - mean*mean;
    float rs = rsqrtf(var + 1e-5f);
    float o0 = (t0-mean)*rs, o1 = (t1-mean)*rs;
    if(outf){ outf[row*D_+tid] = o0; outf[row*D_+tid+256] = o1; }
    if(outb){ outb[row*D_+tid] = f2bf(o0); outb[row*D_+tid+256] = f2bf(o1); }
}

extern "C" void kernel_launch(void* const* d_in, const int* in_sizes, int n_in,
                              void* d_out, int out_size, void* d_ws, size_t ws_size,
                              hipStream_t stream)
{
    const float* z         = (const float*)d_in[0];
    const float* y         = (const float*)d_in[1];
    const float* graph_dec = (const float*)d_in[2];
    const float* graph_enc = (const float*)d_in[3];
    const float* dec_Wk = (const float*)d_in[4];  const float* dec_bk = (const float*)d_in[5];
    const float* dec_Wv = (const float*)d_in[6];  const float* dec_bv = (const float*)d_in[7];
    const float* dec_Wo = (const float*)d_in[8];  const float* dec_bo = (const float*)d_in[9];
    const float* enc_Wk = (const float*)d_in[10]; const float* enc_bk = (const float*)d_in[11];
    const float* enc_Wq = (const float*)d_in[12]; const float* enc_bq = (const float*)d_in[13];
    const float* enc_Wv = (const float*)d_in[14]; const float* enc_bv = (const float*)d_in[15];
    const float* enc_Wo = (const float*)d_in[16]; const float* enc_bo = (const float*)d_in[17];
    const float* fc_W1  = (const float*)d_in[18]; const float* fc_b1  = (const float*)d_in[19];
    const float* fc_W2  = (const float*)d_in[20]; const float* fc_b2  = (const float*)d_in[21];

    char* ws = (char*)d_ws;
    short* gdec  = (short*)(ws + 0x0000000);
    short* genc  = (short*)(ws + 0x0400000);
    short* y_bf  = (short*)(ws + 0x0800000);
    short* z_bf  = (short*)(ws + 0x0C00000);
    short* Kdec  = (short*)(ws + 0x1000000);
    short* Vtdec = (short*)(ws + 0x1400000);
    short* Kenc  = (short*)(ws + 0x1800000);
    short* Vtenc = (short*)(ws + 0x1C00000);
    short* Qenc  = (short*)(ws + 0x2000000);
    short* ctx   = (short*)(ws + 0x2400000);
    float* tmp   = (float*)(ws + 0x2800000);
    float* hbuf  = (float*)(ws + 0x3000000);
    short* h_bf  = (short*)(ws + 0x3800000);
    float* h2    = (float*)(ws + 0x3C00000);
    short* h2_bf = (short*)(ws + 0x4400000);
    short* fc1   = (short*)(ws + 0x4800000);
    short* wKVd  = (short*)(ws + 0x5800000);
    short* wKVe  = (short*)(ws + 0x5900000);
    short* wQet  = (short*)(ws + 0x5A00000);
    short* wOdt  = (short*)(ws + 0x5A80000);
    short* wOet  = (short*)(ws + 0x5B00000);
    short* wF1t  = (short*)(ws + 0x5B80000);
    short* wF2t  = (short*)(ws + 0x5D80000);
    float* outp  = (float*)d_out;

    dim3 B(256);
    // 1) all preprocessing in one dispatch
    prep_kernel<<<dim3(9984),B,0,stream>>>(
        dec_Wk, dec_Wv, enc_Wk, enc_Wv, enc_Wq, dec_Wo, enc_Wo, fc_W1, fc_W2,
        y, z, graph_dec, graph_enc,
        wKVd, wKVe, wQet, wOdt, wOet, wF1t, wF2t, y_bf, z_bf, gdec, genc);
    // 2) dec + enc KV projections in one dispatch
    gemm_projkv_kernel<<<dim3(64,1,16),B,0,stream>>>(
        y_bf, z_bf, wKVd, wKVe, dec_bk, dec_bv, enc_bk, enc_bv,
        Kdec, Vtdec, Kenc, Vtenc);
    // 3) decoder stage — Wo GEMM at 64x64 tiles (grid 512 = 2 blocks/CU)
    attn_kernel<<<dim3(32,64),dim3(512),0,stream>>>(Kdec, Kdec, Vtdec, gdec, ctx, 1);
    gemm_big_kernel<64,64,0,0><<<dim3(64,8),B,0,stream>>>(ctx, wOdt, dec_bo, tmp, 4096, 512, 512);
    ln_kernel<<<dim3(4096),B,0,stream>>>(tmp, y, hbuf, h_bf);
    // 4) encoder-decoder stage
    gemm_projq_kernel<<<dim3(64,1,8),B,0,stream>>>(h_bf, wQet, enc_bq, Qenc);
    attn_kernel<<<dim3(32,64),dim3(512),0,stream>>>(Qenc, Kenc, Vtenc, genc, ctx, 0);
    gemm_big_kernel<64,64,0,0><<<dim3(64,8),B,0,stream>>>(ctx, wOet, enc_bo, tmp, 4096, 512, 512);
    ln_kernel<<<dim3(4096),B,0,stream>>>(tmp, hbuf, h2, h2_bf);
    // 5) MLP — MLP1 at 128x128 (r10 best), MLP2 at 64x64
    gemm_big_kernel<128,128,1,1><<<dim3(32,16),B,0,stream>>>(h2_bf, wF1t, fc_b1, fc1, 4096, 2048, 512);
    gemm_big_kernel<64,64,0,0><<<dim3(64,8),B,0,stream>>>(fc1, wF2t, fc_b2, tmp, 4096, 512, 2048);
    ln_kernel<<<dim3(4096),B,0,stream>>>(tmp, h2, outp, (short*)0);
}

// Round 14
// 360.216 us; speedup vs baseline: 1.0713x; 1.0713x over previous
//
#include <hip/hip_runtime.h>
#include <stdint.h>

typedef short short8 __attribute__((ext_vector_type(8)));
typedef short short4v __attribute__((ext_vector_type(4)));
typedef float floatx4 __attribute__((ext_vector_type(4)));
typedef unsigned uint4v __attribute__((ext_vector_type(4)));

#define H_  8
#define NB_ 4      // batch N
#define S_  1024
#define D_  512
#define KD_ 64

// fused "wait for prefetched global->LDS loads, then block barrier"
#define VM0_BARRIER() asm volatile("s_waitcnt vmcnt(0)\n\ts_barrier" ::: "memory")

__device__ __forceinline__ short f2bf(float f){
    unsigned u = __builtin_bit_cast(unsigned, f);
    u += 0x7fffu + ((u>>16)&1u);
    return (short)(u>>16);
}
__device__ __forceinline__ float wred_addf(float x){
    #pragma unroll
    for(int o=32;o>0;o>>=1) x += __shfl_xor(x,o,64);
    return x;
}
__device__ __forceinline__ float wred_maxf(float x){
    #pragma unroll
    for(int o=32;o>0;o>>=1) x = fmaxf(x,__shfl_xor(x,o,64));
    return x;
}
__device__ __forceinline__ unsigned umaxu(unsigned a, unsigned b){ return a>b?a:b; }
__device__ __forceinline__ unsigned uminu(unsigned a, unsigned b){ return a<b?a:b; }

// DPP-based wave64 reductions: pure VALU, result uniform via readlane.
template<int CTRL, int RMASK, int BC>
__device__ __forceinline__ unsigned dppu(unsigned x){
    return (unsigned)__builtin_amdgcn_update_dpp(0, (int)x, CTRL, RMASK, 0xf, BC);
}
template<int CTRL, int RMASK>
__device__ __forceinline__ unsigned dppu_m1(unsigned x){
    return (unsigned)__builtin_amdgcn_update_dpp((int)0xFFFFFFFF, (int)x, CTRL, RMASK, 0xf, 0);
}
__device__ __forceinline__ unsigned wsum_dpp_u(unsigned x){
    x += dppu<0x111,0xf,1>(x);
    x += dppu<0x112,0xf,1>(x);
    x += dppu<0x114,0xf,1>(x);
    x += dppu<0x118,0xf,1>(x);
    x += dppu<0x142,0xa,0>(x);
    x += dppu<0x143,0xc,0>(x);
    return (unsigned)__builtin_amdgcn_readlane((int)x, 63);
}
__device__ __forceinline__ unsigned wmax_dpp_u(unsigned x){
    x = umaxu(x, dppu<0x111,0xf,1>(x));
    x = umaxu(x, dppu<0x112,0xf,1>(x));
    x = umaxu(x, dppu<0x114,0xf,1>(x));
    x = umaxu(x, dppu<0x118,0xf,1>(x));
    x = umaxu(x, dppu<0x142,0xa,0>(x));
    x = umaxu(x, dppu<0x143,0xc,0>(x));
    return (unsigned)__builtin_amdgcn_readlane((int)x, 63);
}
__device__ __forceinline__ unsigned wmin_dpp_u(unsigned x){
    x = uminu(x, dppu_m1<0x111,0xf>(x));
    x = uminu(x, dppu_m1<0x112,0xf>(x));
    x = uminu(x, dppu_m1<0x114,0xf>(x));
    x = uminu(x, dppu_m1<0x118,0xf>(x));
    x = uminu(x, dppu_m1<0x142,0xa>(x));
    x = uminu(x, dppu_m1<0x143,0xc>(x));
    return (unsigned)__builtin_amdgcn_readlane((int)x, 63);
}
__device__ __forceinline__ float addu_f(float a, unsigned b){
    return a + __builtin_bit_cast(float, b);
}
__device__ __forceinline__ float wsum_dpp_f(float x){
    x = addu_f(x, dppu<0x111,0xf,1>(__builtin_bit_cast(unsigned,x)));
    x = addu_f(x, dppu<0x112,0xf,1>(__builtin_bit_cast(unsigned,x)));
    x = addu_f(x, dppu<0x114,0xf,1>(__builtin_bit_cast(unsigned,x)));
    x = addu_f(x, dppu<0x118,0xf,1>(__builtin_bit_cast(unsigned,x)));
    x = addu_f(x, dppu<0x142,0xa,0>(__builtin_bit_cast(unsigned,x)));
    x = addu_f(x, dppu<0x143,0xc,0>(__builtin_bit_cast(unsigned,x)));
    return __builtin_bit_cast(float, (unsigned)__builtin_amdgcn_readlane((int)__builtin_bit_cast(unsigned, x), 63));
}
__device__ __forceinline__ unsigned cvt_pk_bf16(float a, float b){
    unsigned r;
    asm("v_cvt_pk_bf16_f32 %0, %1, %2" : "=v"(r) : "v"(a), "v"(b));
    return r;
}
// hybrid top-k probe count: 8 elements on VALU (addc + DPP reduce),
// 8 elements on SALU (ballot + popcount).
__device__ __forceinline__ unsigned count128(const unsigned (&kv)[16], unsigned mid){
    unsigned cv = 0u;
    #pragma unroll
    for(int j=0;j<8;j++) cv += (unsigned)(kv[j] >= mid);
    unsigned cs = 0u;
    #pragma unroll
    for(int j=8;j<16;j++) cs += (unsigned)__popcll(__ballot(kv[j] >= mid));
    return wsum_dpp_u(cv) + cs;
}

// ---------------- merged prep: wtrans5 + wtrans4 + cvt2 + graph softmax ----------------
__global__ __launch_bounds__(256) void prep_kernel(
    const float* __restrict__ dWk, const float* __restrict__ dWv,
    const float* __restrict__ eWk, const float* __restrict__ eWv, const float* __restrict__ eWq,
    const float* __restrict__ dWo, const float* __restrict__ eWo,
    const float* __restrict__ W1, const float* __restrict__ W2,
    const float* __restrict__ y, const float* __restrict__ z,
    const float* __restrict__ g0, const float* __restrict__ g1,
    short* __restrict__ wKVd, short* __restrict__ wKVe, short* __restrict__ wQet,
    short* __restrict__ oWod, short* __restrict__ oWoe,
    short* __restrict__ oW1, short* __restrict__ oW2,
    short* __restrict__ y_bf, short* __restrict__ z_bf,
    short* __restrict__ og0, short* __restrict__ og1)
{
    __shared__ float t[32][33];
    int id = blockIdx.x;
    int tid = threadIdx.x;
    if(id < 1280){
        // wtrans5: per-head [512][64] -> [64][512] bf16
        int zz = id >> 5; int rem = id & 31; int by = rem >> 1, bx = rem & 1;
        int w = zz>>3, h = zz&7;
        const float* src; short* dst;
        if(w==0){ src = dWk + h*32768; dst = wKVd + h*65536; }
        else if(w==1){ src = dWv + h*32768; dst = wKVd + h*65536 + 32768; }
        else if(w==2){ src = eWk + h*32768; dst = wKVe + h*65536; }
        else if(w==3){ src = eWv + h*32768; dst = wKVe + h*65536 + 32768; }
        else { src = eWq + h*32768; dst = wQet + h*32768; }
        int c0 = bx*32, r0 = by*32;
        int r = tid>>3, cq = (tid&7)*4;
        #pragma unroll
        for(int i=0;i<4;i++) t[r][cq+i] = src[(r0+r)*64 + c0+cq+i];
        __syncthreads();
        int c = tid>>3, rq = (tid&7)*4;
        #pragma unroll
        for(int i=0;i<4;i++) dst[(c0+c)*512 + r0+rq+i] = f2bf(t[rq+i][c]);
    } else if(id < 3840){
        // wtrans4
        int id2 = id - 1280;
        const float* src; short* dst; int R, C, c0, r0;
        if(id2 < 512){
            src = (id2<256)? dWo : eWo; dst = (id2<256)? oWod : oWoe;
            int tt = id2 & 255; R = 512; C = 512;
            c0 = (tt&15)*32; r0 = (tt>>4)*32;
        } else if(id2 < 1536){
            src = W1; dst = oW1; int tt = id2 - 512; R = 512; C = 2048;
            c0 = (tt&63)*32; r0 = (tt>>6)*32;
        } else {
            src = W2; dst = oW2; int tt = id2 - 1536; R = 2048; C = 512;
            c0 = (tt&15)*32; r0 = (tt>>4)*32;
        }
        int r = tid>>3, cq = (tid&7)*4;
        #pragma unroll
        for(int i=0;i<4;i++) t[r][cq+i] = src[(long)(r0+r)*C + c0+cq+i];
        __syncthreads();
        int c = tid>>3, rq = (tid&7)*4;
        #pragma unroll
        for(int i=0;i<4;i++) dst[(long)(c0+c)*R + r0+rq+i] = f2bf(t[rq+i][c]);
    } else if(id < 7936){
        // cvt2: fp32 -> bf16 for y and z
        int tt = id - 3840;
        int bx = tt & 2047, by = tt >> 11;
        const float* in = by ? z : y;
        short* out = by ? z_bf : y_bf;
        int i = (bx*256 + tid)*4;
        floatx4 v = *(const floatx4*)(in + i);
        short4v r;
        #pragma unroll
        for(int j=0;j<4;j++) r[j] = f2bf(v[j]);
        *(short4v*)(out + i) = r;
    } else {
        // graph softmax -> 0.5*softmax bf16
        int tt = id - 7936;
        int row = tt & 1023, by = tt >> 10;
        const float* g = by ? g1 : g0;
        short* o = by ? og1 : og0;
        const float* gr = g + (long)row*S_;
        short* orow = o + (long)row*S_;
        int wave = tid>>6, lane = tid&63;
        float* red = &t[0][0];
        float v[4]; float mx = -3.0e38f;
        #pragma unroll
        for(int i=0;i<4;i++){ v[i] = gr[tid + 256*i]; mx = fmaxf(mx, v[i]); }
        mx = wred_maxf(mx);
        if(lane==0) red[wave] = mx;
        __syncthreads();
        mx = fmaxf(fmaxf(red[0],red[1]), fmaxf(red[2],red[3]));
        float s = 0.f;
        #pragma unroll
        for(int i=0;i<4;i++){ v[i] = __expf(v[i]-mx); s += v[i]; }
        s = wred_addf(s);
        if(lane==0) red[4+wave] = s;
        __syncthreads();
        s = red[4]+red[5]+red[6]+red[7];
        float inv = 0.5f/s;
        #pragma unroll
        for(int i=0;i<4;i++) orow[tid + 256*i] = f2bf(v[i]*inv);
    }
}

// ---------------- merged dec+enc KV projection (2-phase double-buffered) ----------------
__global__ __launch_bounds__(256) void gemm_projkv_kernel(
    const short* __restrict__ Ay, const short* __restrict__ Az,
    const short* __restrict__ Bd, const short* __restrict__ Be,
    const float* __restrict__ dbk, const float* __restrict__ dbv,
    const float* __restrict__ ebk, const float* __restrict__ ebv,
    short* __restrict__ Kd, short* __restrict__ Vd,
    short* __restrict__ Ke, short* __restrict__ Ve)
{
    __shared__ short As[2][64*32];
    __shared__ short Bs[2][128*32];
    int z = blockIdx.z; int enc = z>>3; int zl = z&7;
    const short* A  = enc ? Az : Ay;
    const short* Bb = (enc ? Be : Bd) + zl*65536;
    const float* b1 = enc ? ebk : dbk;
    const float* b2 = enc ? ebv : dbv;
    short* o1 = enc ? Ke : Kd;
    short* o2 = enc ? Ve : Vd;
    int m0 = blockIdx.x*64;
    int tid = threadIdx.x, wave = tid>>6, lane = tid&63, quad = lane>>4, nl = lane&15;
    int wm = (wave&1)*32, wn = (wave>>1)*64;
    floatx4 acc[2][4];
    #pragma unroll
    for(int i=0;i<2;i++)
        #pragma unroll
        for(int j=0;j<4;j++) acc[i][j] = (floatx4){0.f,0.f,0.f,0.f};
    int r = tid>>2, c = (tid&3)*8;
    auto stage = [&](int b, int k0){
        __builtin_amdgcn_global_load_lds(
            (const __attribute__((address_space(1))) unsigned*)(A + (long)(m0 + r)*512 + k0 + c),
            (__attribute__((address_space(3))) unsigned*)((char*)As[b] + wave*1024), 16, 0, 0);
        #pragma unroll
        for(int i=0;i<2;i++)
            __builtin_amdgcn_global_load_lds(
                (const __attribute__((address_space(1))) unsigned*)(Bb + (long)(r + i*64)*512 + k0 + c),
                (__attribute__((address_space(3))) unsigned*)((char*)Bs[b] + i*4096 + wave*1024), 16, 0, 0);
    };
    stage(0, 0);
    VM0_BARRIER();
    int cur = 0;
    for(int k0=0;k0<512;k0+=32){
        if(k0 + 32 < 512) stage(cur^1, k0+32);
        short8 af[2], bfr[4];
        #pragma unroll
        for(int i=0;i<2;i++) af[i] = *(const short8*)(As[cur] + (wm + i*16 + nl)*32 + quad*8);
        #pragma unroll
        for(int j=0;j<4;j++) bfr[j] = *(const short8*)(Bs[cur] + (wn + j*16 + nl)*32 + quad*8);
        #pragma unroll
        for(int i=0;i<2;i++)
            #pragma unroll
            for(int j=0;j<4;j++)
                acc[i][j] = __builtin_amdgcn_mfma_f32_16x16x32_bf16(af[i],bfr[j],acc[i][j],0,0,0);
        VM0_BARRIER();
        cur ^= 1;
    }
    #pragma unroll
    for(int j=0;j<4;j++){
        int n = wn + j*16 + nl;
        float bv = (n >= 64) ? b2[zl*64 + n - 64] : b1[zl*64 + n];
        #pragma unroll
        for(int i=0;i<2;i++){
            #pragma unroll
            for(int rr=0;rr<4;rr++){
                int m = m0 + wm + i*16 + quad*4 + rr;
                float v = acc[i][j][rr] + bv;
                long zb = (long)(zl*NB_ + (m>>10));
                if(n >= 64) o2[ (zb*KD_ + (n-64))*S_ + (m&1023) ] = f2bf(v);
                else        o1[ (zb*S_ + (m&1023))*KD_ + n ] = f2bf(v);
            }
        }
    }
}

// ---------------- projection GEMM for Q (2-phase double-buffered) ----------------
__global__ __launch_bounds__(256) void gemm_projq_kernel(
    const short* __restrict__ A, const short* __restrict__ Bt,
    const float* __restrict__ b1, short* __restrict__ o1)
{
    __shared__ short As[2][64*32];
    __shared__ short Bs[2][64*32];
    int z = blockIdx.z;
    int m0 = blockIdx.x*64;
    const short* Bb = Bt + (long)z*(64*512);
    int tid = threadIdx.x, wave = tid>>6, lane = tid&63, quad = lane>>4, nl = lane&15;
    int wm = (wave&1)*32, wn = (wave>>1)*32;
    floatx4 acc[2][2];
    #pragma unroll
    for(int i=0;i<2;i++)
        #pragma unroll
        for(int j=0;j<2;j++) acc[i][j] = (floatx4){0.f,0.f,0.f,0.f};
    int r = tid>>2, c = (tid&3)*8;
    auto stage = [&](int b, int k0){
        __builtin_amdgcn_global_load_lds(
            (const __attribute__((address_space(1))) unsigned*)(A + (long)(m0 + r)*512 + k0 + c),
            (__attribute__((address_space(3))) unsigned*)((char*)As[b] + wave*1024), 16, 0, 0);
        __builtin_amdgcn_global_load_lds(
            (const __attribute__((address_space(1))) unsigned*)(Bb + (long)r*512 + k0 + c),
            (__attribute__((address_space(3))) unsigned*)((char*)Bs[b] + wave*1024), 16, 0, 0);
    };
    stage(0, 0);
    VM0_BARRIER();
    int cur = 0;
    for(int k0=0;k0<512;k0+=32){
        if(k0 + 32 < 512) stage(cur^1, k0+32);
        short8 af[2], bfr[2];
        #pragma unroll
        for(int i=0;i<2;i++) af[i] = *(const short8*)(As[cur] + (wm + i*16 + nl)*32 + quad*8);
        #pragma unroll
        for(int j=0;j<2;j++) bfr[j] = *(const short8*)(Bs[cur] + (wn + j*16 + nl)*32 + quad*8);
        #pragma unroll
        for(int i=0;i<2;i++)
            #pragma unroll
            for(int j=0;j<2;j++)
                acc[i][j] = __builtin_amdgcn_mfma_f32_16x16x32_bf16(af[i],bfr[j],acc[i][j],0,0,0);
        VM0_BARRIER();
        cur ^= 1;
    }
    #pragma unroll
    for(int j=0;j<2;j++){
        int n = wn + j*16 + nl;
        float bv = b1[z*64 + n];
        #pragma unroll
        for(int i=0;i<2;i++){
            #pragma unroll
            for(int rr=0;rr<4;rr++){
                int m = m0 + wm + i*16 + quad*4 + rr;
                float v = acc[i][j][rr] + bv;
                long zb = (long)(z*NB_ + (m>>10));
                o1[ (zb*S_ + (m&1023))*KD_ + n ] = f2bf(v);
            }
        }
    }
}

// ---------------- big MFMA GEMM, m97 pattern, 2-phase double-buffered ----------------
template<int TM, int TN, int OUTBF, int RELU>
__global__ __launch_bounds__(256) void gemm_big_kernel(
    const short* __restrict__ A, const short* __restrict__ Bt, const float* __restrict__ bias,
    void* __restrict__ out, int M, int N, int K)
{
    __shared__ short As[2][TM*32];
    __shared__ short Bs[2][TN*32];
    int m0 = blockIdx.x*TM, n0 = blockIdx.y*TN;
    int tid = threadIdx.x, wave = tid>>6, lane = tid&63, quad = lane>>4, nl = lane&15;
    constexpr int MI = TM/32, NI = TN/32;
    int wm = (wave&1)*(TM/2), wn = (wave>>1)*(TN/2);
    floatx4 acc[MI][NI];
    #pragma unroll
    for(int i=0;i<MI;i++)
        #pragma unroll
        for(int j=0;j<NI;j++) acc[i][j] = (floatx4){0.f,0.f,0.f,0.f};

    int r = tid>>2, c = (tid&3)*8;
    auto stage = [&](int b, int k0){
        #pragma unroll
        for(int i=0;i<TM/64;i++)
            __builtin_amdgcn_global_load_lds(
                (const __attribute__((address_space(1))) unsigned*)(A + (long)(m0 + r + i*64)*K + k0 + c),
                (__attribute__((address_space(3))) unsigned*)((char*)As[b] + i*4096 + wave*1024),
                16, 0, 0);
        #pragma unroll
        for(int i=0;i<TN/64;i++)
            __builtin_amdgcn_global_load_lds(
                (const __attribute__((address_space(1))) unsigned*)(Bt + (long)(n0 + r + i*64)*K + k0 + c),
                (__attribute__((address_space(3))) unsigned*)((char*)Bs[b] + i*4096 + wave*1024),
                16, 0, 0);
    };
    stage(0, 0);
    VM0_BARRIER();
    int cur = 0;
    for(int k0=0;k0<K;k0+=32){
        if(k0 + 32 < K) stage(cur^1, k0+32);
        short8 af[MI], bfr[NI];
        #pragma unroll
        for(int i=0;i<MI;i++) af[i] = *(const short8*)(As[cur] + (wm + i*16 + nl)*32 + quad*8);
        #pragma unroll
        for(int j=0;j<NI;j++) bfr[j] = *(const short8*)(Bs[cur] + (wn + j*16 + nl)*32 + quad*8);
        #pragma unroll
        for(int i=0;i<MI;i++)
            #pragma unroll
            for(int j=0;j<NI;j++)
                acc[i][j] = __builtin_amdgcn_mfma_f32_16x16x32_bf16(af[i],bfr[j],acc[i][j],0,0,0);
        VM0_BARRIER();
        cur ^= 1;
    }
    #pragma unroll
    for(int j=0;j<NI;j++){
        int n = n0 + wn + j*16 + nl;
        float bv = bias[n];
        #pragma unroll
        for(int i=0;i<MI;i++){
            #pragma unroll
            for(int rr=0;rr<4;rr++){
                int m = m0 + wm + i*16 + quad*4 + rr;
                float v = acc[i][j][rr] + bv;
                if(RELU) v = fmaxf(v, 0.f);
                if(OUTBF) ((short*)out)[(long)m*N + n] = f2bf(v);
                else      ((float*)out)[(long)m*N + n] = v;
            }
        }
    }
}

// ---------------- fused attention v14: r6 search + causal early-row skip ----------------
// For causal rows with qg < 128 the row has <= 128 finite entries, so the reference
// top-128 threshold is -inf and ALL entries are kept: lo = 0x80 (> masked key 0x7f)
// reproduces it exactly with no search.
__global__ __launch_bounds__(512,6) void attn_kernel(
    const short* __restrict__ Qb, const short* __restrict__ Kb, const short* __restrict__ Vt,
    const short* __restrict__ graph, short* __restrict__ ctx, int causal)
{
    __shared__ short attb[16*1024];   // 32 KiB
    __shared__ float pbuf[16*68];     // 4.25 KiB
    int hn = blockIdx.x, qt = blockIdx.y;
    int h = hn>>2, n = hn&3;
    int q0 = qt*16;
    int tid=threadIdx.x, wave=tid>>6, lane=tid&63, quad=lane>>4, nl=lane&15;

    if(causal){
        uint4v fv = (uint4v){0xff80ff80u,0xff80ff80u,0xff80ff80u,0xff80ff80u};
        #pragma unroll
        for(int i=0;i<4;i++) *(uint4v*)((char*)attb + tid*16 + i*8192) = fv;
        __syncthreads();
    }

    // ---- phase 1: scores -> bf16 LDS (rot 8q), diagonal tile masked to -inf ----
    const short* Qp = Qb + ((long)hn*S_ + q0 + nl)*KD_ + quad*8;
    short8 aq0 = *(const short8*)(Qp);
    short8 aq1 = *(const short8*)(Qp + 32);
    const short* Kp = Kb + (long)hn*S_*KD_;
    int stmax = causal ? qt : 63;
    for(int st=wave; st<=stmax; st+=8){
        const short* kp = Kp + (st*16 + nl)*KD_ + quad*8;
        short8 b0 = *(const short8*)(kp);
        short8 b1 = *(const short8*)(kp + 32);
        floatx4 cc = (floatx4){0.f,0.f,0.f,0.f};
        cc = __builtin_amdgcn_mfma_f32_16x16x32_bf16(aq0,b0,cc,0,0,0);
        cc = __builtin_amdgcn_mfma_f32_16x16x32_bf16(aq1,b1,cc,0,0,0);
        int s = st*16 + nl;
        #pragma unroll
        for(int rr=0;rr<4;rr++){
            int q = quad*4 + rr;
            short val = f2bf(cc[rr]*0.125f);
            if(causal && s > q0 + q) val = (short)0xff80;   // -inf
            attb[q*1024 + ((s + 8*q)&1023)] = val;
        }
    }
    __syncthreads();

    // ---- phase 2: top-128 + softmax + graph blend; 2 sequential rows/wave ----
    #pragma unroll 1
    for(int rp=0; rp<2; ++rp){
        int q = wave*2 + rp;
        int qg = q0 + q;
        short* rowp = attb + q*1024;
        int sb = lane*16;
        int p0 = (sb + 8*q) & 1023;
        const short* grow = graph + (long)qg*1024 + sb;
        uint4v g0 = *(const uint4v*)(grow);
        uint4v g1 = *(const uint4v*)(grow + 8);
        uint4v u0 = *(const uint4v*)(rowp + p0);
        uint4v u1 = *(const uint4v*)(rowp + ((p0+8)&1023));
        unsigned pr[8];
        #pragma unroll
        for(int i=0;i<4;i++){ pr[i] = u0[i]; pr[4+i] = u1[i]; }
        unsigned kv[16];
        #pragma unroll
        for(int i=0;i<8;i++){
            unsigned u = pr[i];
            unsigned kp = u ^ (0x80008000u + ((u>>15)&0x00010001u)*0x7fffu);
            kv[2*i]   = kp & 0xffffu;
            kv[2*i+1] = kp >> 16;
        }
        unsigned a0 = umaxu(kv[0],kv[1]),  a1 = umaxu(kv[2],kv[3]);
        unsigned a2 = umaxu(kv[4],kv[5]),  a3 = umaxu(kv[6],kv[7]);
        unsigned a4 = umaxu(kv[8],kv[9]),  a5 = umaxu(kv[10],kv[11]);
        unsigned a6 = umaxu(kv[12],kv[13]),a7 = umaxu(kv[14],kv[15]);
        unsigned mk = umaxu(umaxu(umaxu(a0,a1),umaxu(a2,a3)), umaxu(umaxu(a4,a5),umaxu(a6,a7)));
        unsigned mks = wmax_dpp_u(mk);
        unsigned lo;
        if(causal && qg < 128){
            // <=128 finite entries: reference threshold is -inf -> keep all finite
            lo = 0x80u;
        } else {
            unsigned lmin = wmin_dpp_u(mk);
            unsigned hi;
            {
                unsigned cnt = count128(kv, lmin);
                if(cnt >= 128u){ lo = lmin; hi = (cnt == 128u) ? (lmin + 1u) : (mks + 1u); }
                else           { lo = 0u;   hi = lmin; }
            }
            while(hi - lo > 1u){
                unsigned mid = (lo + hi) >> 1;
                unsigned cnt = count128(kv, mid);
                if(cnt >= 128u){ lo = mid; if(cnt == 128u) break; }
                else hi = mid;
            }
        }
        // row max as float (uniform)
        unsigned uo = (mks & 0x8000u) ? ((mks & 0x7fffu)<<16) : ((~mks)<<16);
        float mxf = __builtin_bit_cast(float, uo);
        float ev[16]; float sm = 0.f;
        #pragma unroll
        for(int i=0;i<8;i++){
            float f0 = __builtin_bit_cast(float, pr[i] << 16);
            float f1 = __builtin_bit_cast(float, pr[i] & 0xffff0000u);
            float e0 = __expf(f0 - mxf);
            float e1 = __expf(f1 - mxf);
            e0 = (kv[2*i]   >= lo) ? e0 : 0.f;
            e1 = (kv[2*i+1] >= lo) ? e1 : 0.f;
            ev[2*i] = e0; ev[2*i+1] = e1;
            sm += e0 + e1;
        }
        sm = wsum_dpp_f(sm);
        float inv = 0.5f / sm;   // (1-gw) = 0.5; graph holds 0.5*softmax
        uint4v w0, w1;
        #pragma unroll
        for(int i=0;i<4;i++){
            float gl0 = __builtin_bit_cast(float, g0[i] << 16);
            float gh0 = __builtin_bit_cast(float, g0[i] & 0xffff0000u);
            w0[i] = cvt_pk_bf16(fmaf(ev[2*i], inv, gl0), fmaf(ev[2*i+1], inv, gh0));
            float gl1 = __builtin_bit_cast(float, g1[i] << 16);
            float gh1 = __builtin_bit_cast(float, g1[i] & 0xffff0000u);
            w1[i] = cvt_pk_bf16(fmaf(ev[8+2*i], inv, gl1), fmaf(ev[8+2*i+1], inv, gh1));
        }
        *(uint4v*)(rowp + p0) = w0;
        *(uint4v*)(rowp + ((p0+8)&1023)) = w1;
    }
    __syncthreads();

    // ---- phase 3: ctx = att @ V, split over s-halves (sh), v-quarters (vh) ----
    int vh = wave & 3, sh = wave >> 2;
    int v0 = vh*16;
    const short* Vp = Vt + ((long)hn*KD_ + v0 + nl)*S_;
    floatx4 o4 = (floatx4){0.f,0.f,0.f,0.f};
    int arow = nl;
    int sbase = sh*512;
    for(int s0=sbase; s0<sbase+512; s0+=32){
        int cs = (s0 + quad*8 + 8*arow) & 1023;
        short8 ap = *(const short8*)(attb + arow*1024 + cs);
        short8 bv = *(const short8*)(Vp + s0 + quad*8);
        o4 = __builtin_amdgcn_mfma_f32_16x16x32_bf16(ap,bv,o4,0,0,0);
    }
    if(sh==1){
        #pragma unroll
        for(int rr=0;rr<4;rr++) pbuf[(quad*4+rr)*68 + v0 + nl] = o4[rr];
    }
    __syncthreads();
    if(sh==0){
        #pragma unroll
        for(int rr=0;rr<4;rr++){
            int q = quad*4 + rr;
            float v = o4[rr] + pbuf[q*68 + v0 + nl];
            ctx[ ((long)(n*S_ + q0 + q))*512 + h*KD_ + v0 + nl ] = f2bf(v);
        }
    }
}

// ---------------- LayerNorm(x + res) ----------------
__global__ __launch_bounds__(256) void ln_kernel(const float* __restrict__ x, const float* __restrict__ res,
                                                 float* __restrict__ outf, short* __restrict__ outb){
    long row = blockIdx.x;
    const float* xr = x + row*D_;
    const float* rr = res + row*D_;
    int tid = threadIdx.x, wave = tid>>6, lane = tid&63;
    float t0 = xr[tid] + rr[tid];
    float t1 = xr[tid+256] + rr[tid+256];
    float s = t0 + t1, s2 = t0*t0 + t1*t1;
    __shared__ float red[8];
    s = wred_addf(s); s2 = wred_addf(s2);
    if(lane==0){ red[wave] = s; red[4+wave] = s2; }
    __syncthreads();
    s  = red[0]+red[1]+red[2]+red[3];
    s2 = red[4]+red[5]+red[6]+red[7];
    float mean = s*(1.f/512.f);
    float var = s2*(1.f/512.f) - mean*mean;
    float rs = rsqrtf(var + 1e-5f);
    float o0 = (t0-mean)*rs, o1 = (t1-mean)*rs;
    if(outf){ outf[row*D_+tid] = o0; outf[row*D_+tid+256] = o1; }
    if(outb){ outb[row*D_+tid] = f2bf(o0); outb[row*D_+tid+256] = f2bf(o1); }
}

extern "C" void kernel_launch(void* const* d_in, const int* in_sizes, int n_in,
                              void* d_out, int out_size, void* d_ws, size_t ws_size,
                              hipStream_t stream)
{
    const float* z         = (const float*)d_in[0];
    const float* y         = (const float*)d_in[1];
    const float* graph_dec = (const float*)d_in[2];
    const float* graph_enc = (const float*)d_in[3];
    const float* dec_Wk = (const float*)d_in[4];  const float* dec_bk = (const float*)d_in[5];
    const float* dec_Wv = (const float*)d_in[6];  const float* dec_bv = (const float*)d_in[7];
    const float* dec_Wo = (const float*)d_in[8];  const float* dec_bo = (const float*)d_in[9];
    const float* enc_Wk = (const float*)d_in[10]; const float* enc_bk = (const float*)d_in[11];
    const float* enc_Wq = (const float*)d_in[12]; const float* enc_bq = (const float*)d_in[13];
    const float* enc_Wv = (const float*)d_in[14]; const float* enc_bv = (const float*)d_in[15];
    const float* enc_Wo = (const float*)d_in[16]; const float* enc_bo = (const float*)d_in[17];
    const float* fc_W1  = (const float*)d_in[18]; const float* fc_b1  = (const float*)d_in[19];
    const float* fc_W2  = (const float*)d_in[20]; const float* fc_b2  = (const float*)d_in[21];

    char* ws = (char*)d_ws;
    short* gdec  = (short*)(ws + 0x0000000);
    short* genc  = (short*)(ws + 0x0400000);
    short* y_bf  = (short*)(ws + 0x0800000);
    short* z_bf  = (short*)(ws + 0x0C00000);
    short* Kdec  = (short*)(ws + 0x1000000);
    short* Vtdec = (short*)(ws + 0x1400000);
    short* Kenc  = (short*)(ws + 0x1800000);
    short* Vtenc = (short*)(ws + 0x1C00000);
    short* Qenc  = (short*)(ws + 0x2000000);
    short* ctx   = (short*)(ws + 0x2400000);
    float* tmp   = (float*)(ws + 0x2800000);
    float* hbuf  = (float*)(ws + 0x3000000);
    short* h_bf  = (short*)(ws + 0x3800000);
    float* h2    = (float*)(ws + 0x3C00000);
    short* h2_bf = (short*)(ws + 0x4400000);
    short* fc1   = (short*)(ws + 0x4800000);
    short* wKVd  = (short*)(ws + 0x5800000);
    short* wKVe  = (short*)(ws + 0x5900000);
    short* wQet  = (short*)(ws + 0x5A00000);
    short* wOdt  = (short*)(ws + 0x5A80000);
    short* wOet  = (short*)(ws + 0x5B00000);
    short* wF1t  = (short*)(ws + 0x5B80000);
    short* wF2t  = (short*)(ws + 0x5D80000);
    float* outp  = (float*)d_out;

    dim3 B(256);
    // 1) all preprocessing in one dispatch
    prep_kernel<<<dim3(9984),B,0,stream>>>(
        dec_Wk, dec_Wv, enc_Wk, enc_Wv, enc_Wq, dec_Wo, enc_Wo, fc_W1, fc_W2,
        y, z, graph_dec, graph_enc,
        wKVd, wKVe, wQet, wOdt, wOet, wF1t, wF2t, y_bf, z_bf, gdec, genc);
    // 2) dec + enc KV projections in one dispatch
    gemm_projkv_kernel<<<dim3(64,1,16),B,0,stream>>>(
        y_bf, z_bf, wKVd, wKVe, dec_bk, dec_bv, enc_bk, enc_bv,
        Kdec, Vtdec, Kenc, Vtenc);
    // 3) decoder stage — Wo GEMM at 64x64 tiles (grid 512 = 2 blocks/CU)
    attn_kernel<<<dim3(32,64),dim3(512),0,stream>>>(Kdec, Kdec, Vtdec, gdec, ctx, 1);
    gemm_big_kernel<64,64,0,0><<<dim3(64,8),B,0,stream>>>(ctx, wOdt, dec_bo, tmp, 4096, 512, 512);
    ln_kernel<<<dim3(4096),B,0,stream>>>(tmp, y, hbuf, h_bf);
    // 4) encoder-decoder stage
    gemm_projq_kernel<<<dim3(64,1,8),B,0,stream>>>(h_bf, wQet, enc_bq, Qenc);
    attn_kernel<<<dim3(32,64),dim3(512),0,stream>>>(Qenc, Kenc, Vtenc, genc, ctx, 0);
    gemm_big_kernel<64,64,0,0><<<dim3(64,8),B,0,stream>>>(ctx, wOet, enc_bo, tmp, 4096, 512, 512);
    ln_kernel<<<dim3(4096),B,0,stream>>>(tmp, hbuf, h2, h2_bf);
    // 5) MLP — MLP1 at 128x128 (best measured), MLP2 at 64x64
    gemm_big_kernel<128,128,1,1><<<dim3(32,16),B,0,stream>>>(h2_bf, wF1t, fc_b1, fc1, 4096, 2048, 512);
    gemm_big_kernel<64,64,0,0><<<dim3(64,8),B,0,stream>>>(fc1, wF2t, fc_b2, tmp, 4096, 512, 2048);
    ln_kernel<<<dim3(4096),B,0,stream>>>(tmp, h2, outp, (short*)0);
}